// Round 7
// baseline (275.729 us; speedup 1.0000x reference)
//
#include <hip/hip_runtime.h>

// BiasedCrossAttention B=2, LQ=LK=1024, D=1024, H=16, DH=64. fp32 in/out.
// R7: FLAT kernels — no LDS staging, no K-loop barriers. All MFMA fragments are
//     contiguous half8 in global memory (A/W rows k-contiguous; S^T/O^T attn
//     layouts). Register prefetch + full unroll -> compiler emits fine-grained
//     vmcnt; independent waves overlap stalls. (R3/R5/R6 all pinned at the same
//     numbers -> shared staging/barrier path was the suspect.)
// ws (halves, 32 MB): q16|k16|v16 (2M ea) | Qh|Kh|Vt (2M ea) | W16 (4x1M).

typedef _Float16 half8 __attribute__((ext_vector_type(8)));
typedef _Float16 half4_t __attribute__((ext_vector_type(4)));
typedef float f32x4 __attribute__((ext_vector_type(4)));

#define MFMA16(a, b, c) __builtin_amdgcn_mfma_f32_16x16x32_f16((a), (b), (c), 0, 0, 0)

// ------------------------------------------------- cvt fp32->fp16 (acts + weights)
__global__ __launch_bounds__(256) void cvt_f32_f16(
    const float* __restrict__ q, const float* __restrict__ k, const float* __restrict__ v,
    const float* __restrict__ Wq, const float* __restrict__ Wk,
    const float* __restrict__ Wv, const float* __restrict__ Wo,
    _Float16* __restrict__ q16, _Float16* __restrict__ k16, _Float16* __restrict__ v16,
    _Float16* __restrict__ w16) {
  const int y = blockIdx.y;
  if (y >= 3 && blockIdx.x >= 512) return;  // weights are 1M elems (512 blocks)
  const float* s;
  _Float16* d;
  const size_t M = (size_t)1024 * 1024;
  switch (y) {
    case 0: s = q;  d = q16; break;
    case 1: s = k;  d = k16; break;
    case 2: s = v;  d = v16; break;
    case 3: s = Wq; d = w16; break;
    case 4: s = Wk; d = w16 + M; break;
    case 5: s = Wv; d = w16 + 2 * M; break;
    default: s = Wo; d = w16 + 3 * M; break;
  }
  const size_t i = ((size_t)blockIdx.x * 256 + threadIdx.x) * 8;
  const float4 a = *(const float4*)(s + i);
  const float4 bvv = *(const float4*)(s + i + 4);
  half8 h;
  h[0] = (_Float16)a.x; h[1] = (_Float16)a.y; h[2] = (_Float16)a.z; h[3] = (_Float16)a.w;
  h[4] = (_Float16)bvv.x; h[5] = (_Float16)bvv.y; h[6] = (_Float16)bvv.z; h[7] = (_Float16)bvv.w;
  *(half8*)(d + i) = h;
}

// ------------------------------------------------- flat GEMM C = X @ W^T + bias
// Block 256 thr = 4 waves (2m x 2n) covering 64m x 128n; wave tile 32x64
// (2x4 MFMA tiles). K=1024 in 32 steps of 32; triple-buffered register
// fragments, depth-2 prefetch, fully unrolled, ZERO barriers / operand LDS.
__global__ __launch_bounds__(256) void fmm(
    const _Float16* __restrict__ Aq, const _Float16* __restrict__ Ak,
    const _Float16* __restrict__ Av, const _Float16* __restrict__ W16,
    const float* __restrict__ c0, const float* __restrict__ c1,
    const float* __restrict__ c2, _Float16* __restrict__ Dq,
    _Float16* __restrict__ Dk, _Float16* __restrict__ Dvt,
    float* __restrict__ Df, int is_final) {
  __shared__ __align__(16) _Float16 Ct[128 * 72];  // z==2 transpose epilogue only

  const int tid = threadIdx.x;
  const int wv = tid >> 6, ln = tid & 63;
  const int quad = ln >> 4, col = ln & 15;
  const int wm = wv >> 1, wn = wv & 1;
  const int m0 = blockIdx.y * 64 + wm * 32;
  const int n0 = blockIdx.x * 128 + wn * 64;
  const int z = blockIdx.z;

  const _Float16* A = (z == 0) ? Aq : (z == 1) ? Ak : Av;
  const _Float16* Bw = W16 + (size_t)z * 1024 * 1024;
  const float* bias = (z == 0) ? c0 : (z == 1) ? c1 : c2;

  // fragment base pointers: contiguous half8 at (row)*1024 + quad*8 (+ s*32)
  const _Float16* Ap0 = A + (size_t)(m0 + col) * 1024 + quad * 8;
  const _Float16* Ap1 = Ap0 + (size_t)16 * 1024;
  const _Float16* Bp0 = Bw + (size_t)(n0 + col) * 1024 + quad * 8;
  const _Float16* Bp1 = Bp0 + (size_t)16 * 1024;
  const _Float16* Bp2 = Bp0 + (size_t)32 * 1024;
  const _Float16* Bp3 = Bp0 + (size_t)48 * 1024;

  const f32x4 zero4 = {0.f, 0.f, 0.f, 0.f};
  f32x4 acc[2][4];
#pragma unroll
  for (int i = 0; i < 2; ++i)
#pragma unroll
    for (int j = 0; j < 4; ++j) acc[i][j] = zero4;

  half8 af[3][2], bf[3][4];
#define LDSTEP(buf, kofs)                              \
  do {                                                 \
    af[buf][0] = *(const half8*)(Ap0 + (kofs));        \
    af[buf][1] = *(const half8*)(Ap1 + (kofs));        \
    bf[buf][0] = *(const half8*)(Bp0 + (kofs));        \
    bf[buf][1] = *(const half8*)(Bp1 + (kofs));        \
    bf[buf][2] = *(const half8*)(Bp2 + (kofs));        \
    bf[buf][3] = *(const half8*)(Bp3 + (kofs));        \
  } while (0)

  LDSTEP(0, 0);
  LDSTEP(1, 32);
#pragma unroll
  for (int s = 0; s < 32; ++s) {
    if (s < 30) {
      const int nb = (s + 2) % 3;
      LDSTEP(nb, (s + 2) * 32);
    }
    const int cb = s % 3;
#pragma unroll
    for (int mi = 0; mi < 2; ++mi)
#pragma unroll
      for (int ni = 0; ni < 4; ++ni)
        acc[mi][ni] = MFMA16(af[cb][mi], bf[cb][ni], acc[mi][ni]);
  }
#undef LDSTEP

  float bv[4];
#pragma unroll
  for (int ni = 0; ni < 4; ++ni) bv[ni] = bias[n0 + ni * 16 + col];

  if (is_final) {
#pragma unroll
    for (int mi = 0; mi < 2; ++mi) {
      const int m_g = m0 + mi * 16 + quad * 4;
#pragma unroll
      for (int ni = 0; ni < 4; ++ni) {
        const int n_g = n0 + ni * 16 + col;
#pragma unroll
        for (int r = 0; r < 4; ++r)
          Df[(size_t)(m_g + r) * 1024 + n_g] = acc[mi][ni][r] + bv[ni];
      }
    }
  } else if (z < 2) {
    _Float16* D = z ? Dk : Dq;
#pragma unroll
    for (int mi = 0; mi < 2; ++mi) {
      const int m_g = m0 + mi * 16 + quad * 4;
#pragma unroll
      for (int ni = 0; ni < 4; ++ni) {
        const int n_g = n0 + ni * 16 + col;
        const int h = n_g >> 6, dh = n_g & 63;
#pragma unroll
        for (int r = 0; r < 4; ++r) {
          const int b = (m_g + r) >> 10, l = (m_g + r) & 1023;
          D[((size_t)((b * 16 + h) * 1024) + l) * 64 + dh] =
              (_Float16)(acc[mi][ni][r] + bv[ni]);
        }
      }
    }
  } else {
    // transpose 64x128 block through LDS -> Vt[bh][dh][l]
#pragma unroll
    for (int mi = 0; mi < 2; ++mi) {
      const int ml = wm * 32 + mi * 16 + quad * 4;
#pragma unroll
      for (int ni = 0; ni < 4; ++ni) {
        const int nl = wn * 64 + ni * 16 + col;
#pragma unroll
        for (int r = 0; r < 4; ++r)
          Ct[(size_t)nl * 72 + ml + r] = (_Float16)(acc[mi][ni][r] + bv[ni]);
      }
    }
    __syncthreads();
#pragma unroll
    for (int it = 0; it < 4; ++it) {
      const int ci = it * 256 + tid;
      const int n = ci >> 3;        // local n 0..127
      const int mc = (ci & 7) * 8;  // local m chunk
      const half8 hv = *(const half8*)(Ct + (size_t)n * 72 + mc);
      const int n_g = blockIdx.x * 128 + n;
      const int h = n_g >> 6, dh = n_g & 63;
      const int m_g = blockIdx.y * 64 + mc;
      const int b = m_g >> 10, l = m_g & 1023;
      *(half8*)(Dvt + ((size_t)((b * 16 + h) * 64 + dh)) * 1024 + l) = hv;
    }
  }
}

// ------------------------------------------------- flat flash attention
// grid (LQ/32, B*H), 4 waves: (khalf=wv>>1, qsub=wv&1); 16 q-rows x 512 keys.
// K/V/bias/mask fragments direct from global, K+bias+mask prefetched one
// 64-key block ahead (register), V issued at iter start. No mid-loop barriers.
// P roundtrip via per-wave LDS; split-K merge with one barrier pair at end.
__global__ __launch_bounds__(256) void fattn(
    const _Float16* __restrict__ Qh, const _Float16* __restrict__ Kh,
    const _Float16* __restrict__ Vt, const float* __restrict__ biasL,
    const int* __restrict__ kpm, _Float16* __restrict__ AO) {
  __shared__ __align__(16) _Float16 Pt[4][1024];  // per-wave P; merge reuses as Ox
  __shared__ float MlS[256];

  const int tid = threadIdx.x;
  const int wv = tid >> 6, ln = tid & 63;
  const int quad = ln >> 4, col = ln & 15;
  const int qsub = wv & 1, khalf = wv >> 1;
  const int q0 = blockIdx.x * 32;
  const int bh = blockIdx.y;
  const int b = bh >> 4, hh = bh & 15;
  const int qg = q0 + qsub * 16 + col;

  const _Float16* Qp = Qh + ((size_t)bh * 1024 + qg) * 64;
  const half8 bq0 = *(const half8*)(Qp + quad * 8);
  const half8 bq1 = *(const half8*)(Qp + 32 + quad * 8);

  const _Float16* Kb = Kh + (size_t)bh * 1024 * 64;
  const _Float16* Vb = Vt + (size_t)bh * 64 * 1024;
  const float* biasRow = biasL + ((size_t)(b * 1024 + qg)) * 1024;
  const int* kpmRow = kpm + b * 1024;

  auto loadK = [&](int it, half8* kf) {
    const int koff = khalf * 512 + it * 64;
#pragma unroll
    for (int mi = 0; mi < 4; ++mi) {
      const _Float16* Kp = Kb + (size_t)(koff + mi * 16 + col) * 64;
      kf[mi * 2 + 0] = *(const half8*)(Kp + quad * 8);
      kf[mi * 2 + 1] = *(const half8*)(Kp + 32 + quad * 8);
    }
  };
  auto loadBM = [&](int it, f32x4* bb, int4* mk) {
    const int koff = khalf * 512 + it * 64;
#pragma unroll
    for (int mi = 0; mi < 4; ++mi) {
      const int kg = koff + mi * 16 + quad * 4;
      mk[mi] = *(const int4*)&kpmRow[kg];
      bb[mi] = *(const f32x4*)&biasRow[kg];
    }
  };

  const f32x4 zero4 = {0.f, 0.f, 0.f, 0.f};
  f32x4 o[4];
#pragma unroll
  for (int ni = 0; ni < 4; ++ni) o[ni] = zero4;
  float m_i = -1e30f, l_i = 0.f;
  _Float16* Pw = Pt[wv];

  half8 kfA[8];
  f32x4 bbA[4];
  int4 mkA[4];
  loadK(0, kfA);
  loadBM(0, bbA, mkA);

#pragma unroll
  for (int it = 0; it < 8; ++it) {
    // V for this block (needed after softmax -> plenty of in-iter distance)
    half8 vf[8];
    const int koff = khalf * 512 + it * 64;
#pragma unroll
    for (int ni = 0; ni < 4; ++ni) {
      const _Float16* Vp = Vb + (size_t)(ni * 16 + col) * 1024 + koff;
      vf[ni * 2 + 0] = *(const half8*)(Vp + quad * 8);
      vf[ni * 2 + 1] = *(const half8*)(Vp + 32 + quad * 8);
    }

    // S^T = K Q^T from prefetched K fragments
    f32x4 s[4];
#pragma unroll
    for (int mi = 0; mi < 4; ++mi) {
      f32x4 a4 = zero4;
      a4 = MFMA16(kfA[mi * 2 + 0], bq0, a4);
      a4 = MFMA16(kfA[mi * 2 + 1], bq1, a4);
      s[mi] = a4;
    }

    // prefetch next block's K + bias + mask (registers; full unroll renames)
    half8 kfB[8];
    f32x4 bbB[4];
    int4 mkB[4];
    if (it < 7) {
      loadK(it + 1, kfB);
      loadBM(it + 1, bbB, mkB);
    }

    // mask + bias
#pragma unroll
    for (int mi = 0; mi < 4; ++mi) {
      const int* mp = (const int*)&mkA[mi];
#pragma unroll
      for (int r = 0; r < 4; ++r)
        s[mi][r] = mp[r] ? -1e9f : s[mi][r] * 0.125f + bbA[mi][r];
    }

    // per-lane online softmax
    float rm = -1e30f;
#pragma unroll
    for (int mi = 0; mi < 4; ++mi)
#pragma unroll
      for (int r = 0; r < 4; ++r) rm = fmaxf(rm, s[mi][r]);
    rm = fmaxf(rm, __shfl_xor(rm, 16));
    rm = fmaxf(rm, __shfl_xor(rm, 32));
    const float mn = fmaxf(m_i, rm);
    const float alpha = __expf(m_i - mn);
    m_i = mn;
    float ps = 0.f;
#pragma unroll
    for (int mi = 0; mi < 4; ++mi)
#pragma unroll
      for (int r = 0; r < 4; ++r) {
        const float p = __expf(s[mi][r] - mn);
        s[mi][r] = p;
        ps += p;
      }
    ps += __shfl_xor(ps, 16);
    ps += __shfl_xor(ps, 32);
    l_i = l_i * alpha + ps;
#pragma unroll
    for (int ni = 0; ni < 4; ++ni)
#pragma unroll
      for (int r = 0; r < 4; ++r) o[ni][r] *= alpha;

    // P^T -> per-wave LDS (in-wave ordering only)
#pragma unroll
    for (int mi = 0; mi < 4; ++mi) {
      half4_t h;
      h[0] = (_Float16)s[mi][0]; h[1] = (_Float16)s[mi][1];
      h[2] = (_Float16)s[mi][2]; h[3] = (_Float16)s[mi][3];
      const int kloc = mi * 16 + quad * 4;
      const int chunk = kloc >> 3;
      *(half4_t*)(Pw + col * 64 + (((chunk ^ (col & 7)) << 3) | (kloc & 7))) = h;
    }
    const half8 p0 = *(const half8*)(Pw + col * 64 + (((0 + (quad)) ^ (col & 7)) << 3));
    const half8 p1 = *(const half8*)(Pw + col * 64 + (((4 + quad) ^ (col & 7)) << 3));

    // O^T += V^T P^T
#pragma unroll
    for (int ni = 0; ni < 4; ++ni) {
      o[ni] = MFMA16(vf[ni * 2 + 0], p0, o[ni]);
      o[ni] = MFMA16(vf[ni * 2 + 1], p1, o[ni]);
    }

    // rotate prefetch (renamed away under full unroll)
    if (it < 7) {
#pragma unroll
      for (int j = 0; j < 8; ++j) kfA[j] = kfB[j];
#pragma unroll
      for (int mi = 0; mi < 4; ++mi) { bbA[mi] = bbB[mi]; mkA[mi] = mkB[mi]; }
    }
  }

  // split-K merge (khalf 1 -> LDS -> khalf 0)
  __syncthreads();
  f32x4* Ox = (f32x4*)&Pt[0][0];  // 8 KB, P dead
  if (khalf == 1) {
#pragma unroll
    for (int ni = 0; ni < 4; ++ni) Ox[(qsub * 4 + ni) * 64 + ln] = o[ni];
    MlS[qsub * 64 + ln] = m_i;
    MlS[128 + qsub * 64 + ln] = l_i;
  }
  __syncthreads();
  if (khalf == 0) {
    const float m2 = MlS[qsub * 64 + ln];
    const float l2 = MlS[128 + qsub * 64 + ln];
    const float ms = fmaxf(m_i, m2);
    const float w1 = __expf(m_i - ms);
    const float w2 = __expf(m2 - ms);
    const float inv = 1.0f / (l_i * w1 + l2 * w2);
#pragma unroll
    for (int ni = 0; ni < 4; ++ni) {
      const f32x4 o2 = Ox[(qsub * 4 + ni) * 64 + ln];
      half4_t h;
#pragma unroll
      for (int r = 0; r < 4; ++r)
        h[r] = (_Float16)((o[ni][r] * w1 + o2[r] * w2) * inv);
      *(half4_t*)&AO[((size_t)(b * 1024 + qg)) * 1024 + hh * 64 + ni * 16 + quad * 4] = h;
    }
  }
}

extern "C" void kernel_launch(void* const* d_in, const int* in_sizes, int n_in,
                              void* d_out, int out_size, void* d_ws, size_t ws_size,
                              hipStream_t stream) {
  (void)in_sizes; (void)n_in; (void)out_size; (void)ws_size;
  const float* q = (const float*)d_in[0];
  const float* k = (const float*)d_in[1];
  const float* v = (const float*)d_in[2];
  const float* Wq = (const float*)d_in[3];
  const float* bq = (const float*)d_in[4];
  const float* Wk = (const float*)d_in[5];
  const float* bk = (const float*)d_in[6];
  const float* Wv = (const float*)d_in[7];
  const float* bv = (const float*)d_in[8];
  const float* Wo = (const float*)d_in[9];
  const float* bo = (const float*)d_in[10];
  const float* lb = (const float*)d_in[11];
  const int* kpm = (const int*)d_in[12];
  float* out = (float*)d_out;

  const size_t NT = (size_t)2 * 1024 * 1024;
  _Float16* q16 = (_Float16*)d_ws;
  _Float16* k16 = q16 + NT;
  _Float16* v16 = k16 + NT;
  _Float16* Qh = v16 + NT;
  _Float16* Kh = Qh + NT;
  _Float16* Vt = Kh + NT;
  _Float16* w16 = Vt + NT;  // 4 x 1M halves (Wq,Wk,Wv,Wo)
  _Float16* AO = q16;       // q16 dead after projections

  cvt_f32_f16<<<dim3(1024, 7), 256, 0, stream>>>(q, k, v, Wq, Wk, Wv, Wo,
                                                 q16, k16, v16, w16);
  fmm<<<dim3(8, 32, 3), 256, 0, stream>>>(q16, k16, v16, w16, bq, bk, bv,
                                          Qh, Kh, Vt, nullptr, 0);
  fattn<<<dim3(32, 32), 256, 0, stream>>>(Qh, Kh, Vt, lb, kpm, AO);
  fmm<<<dim3(8, 32, 1), 256, 0, stream>>>(AO, nullptr, nullptr, w16 + 3 * NT / 2,
                                          bo, nullptr, nullptr, nullptr, nullptr,
                                          nullptr, out, 1);
}

// Round 8
// 182.476 us; speedup vs baseline: 1.5110x; 1.5110x over previous
//
#include <hip/hip_runtime.h>

// BiasedCrossAttention B=2, LQ=LK=1024, D=1024, H=16, DH=64. fp32 in/out.
// R8: in-block split-K GEMMs (512 thr = 8 waves: 4 wave-tiles x 2 K-halves,
//     LDS merge) -> 2x resident waves at unchanged FLOP/byte. Attn = R5's
//     measured-best staged version (47 us, wave count shown non-binding).
// ws (halves, 32 MB): q16|k16|v16 (2M ea) | Qh|Kh|Vt (2M ea) | W16 (4x1M).

typedef _Float16 half8 __attribute__((ext_vector_type(8)));
typedef _Float16 half4_t __attribute__((ext_vector_type(4)));
typedef float f32x4 __attribute__((ext_vector_type(4)));

#define MFMA16(a, b, c) __builtin_amdgcn_mfma_f32_16x16x32_f16((a), (b), (c), 0, 0, 0)

__device__ __forceinline__ void gload16(const void* g, void* l) {
  __builtin_amdgcn_global_load_lds(
      (const __attribute__((address_space(1))) unsigned int*)g,
      (__attribute__((address_space(3))) unsigned int*)l, 16, 0, 0);
}

// Rows of 64 halves (8 x 16B chunks), physical chunk = logical ^ (row & 7).
__device__ __forceinline__ half8 frag_ld(const _Float16* t, int row, int ck) {
  return *(const half8*)(t + row * 64 + (((ck ^ (row & 7)) << 3)));
}

// ------------------------------------------------- cvt fp32->fp16 (acts + weights)
__global__ __launch_bounds__(256) void cvt_f32_f16(
    const float* __restrict__ q, const float* __restrict__ k, const float* __restrict__ v,
    const float* __restrict__ Wq, const float* __restrict__ Wk,
    const float* __restrict__ Wv, const float* __restrict__ Wo,
    _Float16* __restrict__ q16, _Float16* __restrict__ k16, _Float16* __restrict__ v16,
    _Float16* __restrict__ w16) {
  const int y = blockIdx.y;
  if (y >= 3 && blockIdx.x >= 512) return;  // weights are 1M elems (512 blocks)
  const float* s;
  _Float16* d;
  const size_t M = (size_t)1024 * 1024;
  switch (y) {
    case 0: s = q;  d = q16; break;
    case 1: s = k;  d = k16; break;
    case 2: s = v;  d = v16; break;
    case 3: s = Wq; d = w16; break;
    case 4: s = Wk; d = w16 + M; break;
    case 5: s = Wv; d = w16 + 2 * M; break;
    default: s = Wo; d = w16 + 3 * M; break;
  }
  const size_t i = ((size_t)blockIdx.x * 256 + threadIdx.x) * 8;
  const float4 a = *(const float4*)(s + i);
  const float4 bvv = *(const float4*)(s + i + 4);
  half8 h;
  h[0] = (_Float16)a.x; h[1] = (_Float16)a.y; h[2] = (_Float16)a.z; h[3] = (_Float16)a.w;
  h[4] = (_Float16)bvv.x; h[5] = (_Float16)bvv.y; h[6] = (_Float16)bvv.z; h[7] = (_Float16)bvv.w;
  *(half8*)(d + i) = h;
}

// ------------------------------------------------- split-K GEMM C = X @ W^T + bias
// 512 thr = 8 waves. khalf = wv>>2 owns K in [khalf*512, +512), 8 iters of BK=64.
// Wave-tile 32x64 (2x4 MFMA). Per-khalf LDS: As 64x64 + Bs 128x64 (24 KB).
// End: khalf1 -> LDS f32 partials -> khalf0 adds + epilogue.  LDS 50 KB total.
__global__ __launch_bounds__(512, 6) void mm8(
    const _Float16* __restrict__ Aq, const _Float16* __restrict__ Ak,
    const _Float16* __restrict__ Av, const _Float16* __restrict__ W16,
    const float* __restrict__ c0, const float* __restrict__ c1,
    const float* __restrict__ c2, _Float16* __restrict__ Dq,
    _Float16* __restrict__ Dk, _Float16* __restrict__ Dvt,
    float* __restrict__ Df, int is_final) {
  __shared__ __align__(16) _Float16 lds[25600];  // 2 x 12288 staging; merge: f32[64][128] at 0, Ct at half-ofs 16384

  const int tid = threadIdx.x;
  const int wv = tid >> 6, ln = tid & 63;
  const int quad = ln >> 4, col = ln & 15;
  const int khalf = wv >> 2, lw = wv & 3;
  const int wm = lw >> 1, wn = lw & 1;
  const int n0 = blockIdx.x * 128;
  const int m0 = blockIdx.y * 64;
  const int z = blockIdx.z;
  const int kbase = khalf * 512;

  const _Float16* A = (z == 0) ? Aq : (z == 1) ? Ak : Av;
  const _Float16* Bw = W16 + (size_t)z * 1024 * 1024;
  const float* bias = (z == 0) ? c0 : (z == 1) ? c1 : c2;

  _Float16* As = lds + khalf * 12288;
  _Float16* Bs = As + 4096;

  const f32x4 zero4 = {0.f, 0.f, 0.f, 0.f};
  f32x4 acc[2][4];
#pragma unroll
  for (int i = 0; i < 2; ++i)
#pragma unroll
    for (int j = 0; j < 4; ++j) acc[i][j] = zero4;

  for (int it = 0; it < 8; ++it) {
    const int k0 = kbase + it * 64;
    __syncthreads();
    // each k-half's 256 threads stage 1536 chunks (A 512 + B 1024), 6 each
#pragma unroll
    for (int j = 0; j < 6; ++j) {
      const int ci = j * 256 + lw * 64 + ln;
      const _Float16* src;
      if (ci < 512) {
        const int row = ci >> 3, lc = (ci & 7) ^ (row & 7);
        src = A + (size_t)(m0 + row) * 1024 + k0 + lc * 8;
      } else {
        const int di = ci - 512;
        const int row = di >> 3, lc = (di & 7) ^ (row & 7);
        src = Bw + (size_t)(n0 + row) * 1024 + k0 + lc * 8;
      }
      gload16(src, As + (size_t)(j * 256 + lw * 64) * 8);
    }
    __syncthreads();
#pragma unroll
    for (int kk = 0; kk < 2; ++kk) {
      half8 af[2], bf[4];
#pragma unroll
      for (int mi = 0; mi < 2; ++mi)
        af[mi] = frag_ld(As, wm * 32 + mi * 16 + col, kk * 4 + quad);
#pragma unroll
      for (int ni = 0; ni < 4; ++ni)
        bf[ni] = frag_ld(Bs, wn * 64 + ni * 16 + col, kk * 4 + quad);
#pragma unroll
      for (int mi = 0; mi < 2; ++mi)
#pragma unroll
        for (int ni = 0; ni < 4; ++ni)
          acc[mi][ni] = MFMA16(af[mi], bf[ni], acc[mi][ni]);
    }
  }

  // ---- split-K merge through LDS
  __syncthreads();  // staging LDS dead
  float* Macc = (float*)lds;  // [64][128] fp32 = 32 KB
  if (khalf == 1) {
#pragma unroll
    for (int mi = 0; mi < 2; ++mi)
#pragma unroll
      for (int ni = 0; ni < 4; ++ni) {
        const int ml = wm * 32 + mi * 16 + quad * 4;
        const int nl = wn * 64 + ni * 16 + col;
#pragma unroll
        for (int r = 0; r < 4; ++r)
          Macc[(size_t)(ml + r) * 128 + nl] = acc[mi][ni][r];
      }
  }
  __syncthreads();  // partials visible
  if (khalf == 0) {
#pragma unroll
    for (int mi = 0; mi < 2; ++mi)
#pragma unroll
      for (int ni = 0; ni < 4; ++ni) {
        const int ml = wm * 32 + mi * 16 + quad * 4;
        const int nl = wn * 64 + ni * 16 + col;
#pragma unroll
        for (int r = 0; r < 4; ++r)
          acc[mi][ni][r] += Macc[(size_t)(ml + r) * 128 + nl];
      }
  }

  float bv[4];
#pragma unroll
  for (int ni = 0; ni < 4; ++ni) bv[ni] = bias[n0 + wn * 64 + ni * 16 + col];

  if (z == 2 && !is_final) {
    // Vt transpose epilogue: khalf0 writes Ct (halves) above Macc, all sync, khalf0 stores
    _Float16* Ct = lds + 16384;  // byte ofs 32768: [128][72] halves = 18 KB (total 50 KB)
    if (khalf == 0) {
#pragma unroll
      for (int mi = 0; mi < 2; ++mi)
#pragma unroll
        for (int ni = 0; ni < 4; ++ni) {
          const int ml = wm * 32 + mi * 16 + quad * 4;
          const int nl = wn * 64 + ni * 16 + col;
#pragma unroll
          for (int r = 0; r < 4; ++r)
            Ct[(size_t)nl * 72 + ml + r] = (_Float16)(acc[mi][ni][r] + bv[ni]);
        }
    }
    __syncthreads();  // Ct visible (all 512 threads reach this)
    if (khalf == 0) {
#pragma unroll
      for (int itc = 0; itc < 4; ++itc) {
        const int ci = itc * 256 + (lw * 64 + ln);
        const int n = ci >> 3;        // local n 0..127
        const int mc = (ci & 7) * 8;  // local m chunk
        const half8 hv = *(const half8*)(Ct + (size_t)n * 72 + mc);
        const int n_g = n0 + n;
        const int h = n_g >> 6, dh = n_g & 63;
        const int m_g = m0 + mc;
        const int b = m_g >> 10, l = m_g & 1023;
        *(half8*)(Dvt + ((size_t)((b * 16 + h) * 64 + dh)) * 1024 + l) = hv;
      }
    }
  } else if (khalf == 0) {
    if (is_final) {
#pragma unroll
      for (int mi = 0; mi < 2; ++mi) {
        const int m_g = m0 + wm * 32 + mi * 16 + quad * 4;
#pragma unroll
        for (int ni = 0; ni < 4; ++ni) {
          const int n_g = n0 + wn * 64 + ni * 16 + col;
#pragma unroll
          for (int r = 0; r < 4; ++r)
            Df[(size_t)(m_g + r) * 1024 + n_g] = acc[mi][ni][r] + bv[ni];
        }
      }
    } else {
      _Float16* D = z ? Dk : Dq;
#pragma unroll
      for (int mi = 0; mi < 2; ++mi) {
        const int m_g = m0 + wm * 32 + mi * 16 + quad * 4;
#pragma unroll
        for (int ni = 0; ni < 4; ++ni) {
          const int n_g = n0 + wn * 64 + ni * 16 + col;
          const int h = n_g >> 6, dh = n_g & 63;
#pragma unroll
          for (int r = 0; r < 4; ++r) {
            const int b = (m_g + r) >> 10, l = (m_g + r) & 1023;
            D[((size_t)((b * 16 + h) * 1024) + l) * 64 + dh] =
                (_Float16)(acc[mi][ni][r] + bv[ni]);
          }
        }
      }
    }
  }
}

// ------------------------------------------------- flash attention (R5 verbatim, 47.3 us)
// grid (LQ/32, B*H), 4 waves: wave = (khalf=wv>>1, qsub=wv&1); 16 q-rows x 512 keys.
__global__ __launch_bounds__(256) void attn(
    const _Float16* __restrict__ Qh, const _Float16* __restrict__ Kh,
    const _Float16* __restrict__ Vt, const float* __restrict__ biasL,
    const int* __restrict__ kpm, _Float16* __restrict__ AO) {
  __shared__ __align__(16) _Float16 KV[4][4096];  // K_h0 | K_h1 | V_h0 | V_h1 (swizzled)
  __shared__ __align__(16) _Float16 Pt[4][1024];  // per-wave P; reused as f32x4 Ox[512]

  const int tid = threadIdx.x;
  const int wv = tid >> 6, ln = tid & 63;
  const int quad = ln >> 4, col = ln & 15;
  const int qsub = wv & 1, khalf = wv >> 1;
  const int q0 = blockIdx.x * 32;
  const int bh = blockIdx.y;
  const int b = bh >> 4, hh = bh & 15;
  const int qg = q0 + qsub * 16 + col;  // this lane's softmax row

  const _Float16* Qp = Qh + ((size_t)bh * 1024 + qg) * 64;
  const half8 bq0 = *(const half8*)(Qp + quad * 8);
  const half8 bq1 = *(const half8*)(Qp + 32 + quad * 8);

  const f32x4 zero4 = {0.f, 0.f, 0.f, 0.f};
  f32x4 o[4];
#pragma unroll
  for (int ni = 0; ni < 4; ++ni) o[ni] = zero4;
  float m_i = -1e30f, l_i = 0.f;

  _Float16* Pw = Pt[wv];
  const _Float16* Ks = KV[khalf];
  const _Float16* Vs = KV[2 + khalf];
  const float* biasRow = biasL + ((size_t)(b * 1024 + qg)) * 1024;
  const int* kpmRow = kpm + b * 1024;

  const int stage_koff_base = (wv & 1) * 512;  // tiles 0,2 -> h0; 1,3 -> h1

  for (int it = 0; it < 8; ++it) {
    const int koff = khalf * 512 + it * 64;
    const int skoff = stage_koff_base + it * 64;

    __syncthreads();
#pragma unroll
    for (int j = 0; j < 8; ++j) {
      const int ci = j * 64 + ln;
      const int row = ci >> 3;
      const int lc = (ci & 7) ^ (row & 7);
      const void* src =
          (wv < 2) ? (const void*)(Kh + ((size_t)bh * 1024 + skoff + row) * 64 + lc * 8)
                   : (const void*)(Vt + ((size_t)bh * 64 + row) * 1024 + skoff + lc * 8);
      gload16(src, KV[wv] + j * 512);
    }
    f32x4 bb[4];
    int4 mk4[4];
#pragma unroll
    for (int mi = 0; mi < 4; ++mi) {
      const int kg = koff + mi * 16 + quad * 4;
      mk4[mi] = *(const int4*)&kpmRow[kg];
      bb[mi] = *(const f32x4*)&biasRow[kg];
    }
    __syncthreads();

    f32x4 s[4];
#pragma unroll
    for (int mi = 0; mi < 4; ++mi) {
      f32x4 a4 = zero4;
      a4 = MFMA16(frag_ld(Ks, mi * 16 + col, quad), bq0, a4);
      a4 = MFMA16(frag_ld(Ks, mi * 16 + col, 4 + quad), bq1, a4);
      s[mi] = a4;
    }
#pragma unroll
    for (int mi = 0; mi < 4; ++mi) {
      const int* mp = (const int*)&mk4[mi];
#pragma unroll
      for (int r = 0; r < 4; ++r)
        s[mi][r] = mp[r] ? -1e9f : s[mi][r] * 0.125f + bb[mi][r];
    }

    float rm = -1e30f;
#pragma unroll
    for (int mi = 0; mi < 4; ++mi)
#pragma unroll
      for (int r = 0; r < 4; ++r) rm = fmaxf(rm, s[mi][r]);
    rm = fmaxf(rm, __shfl_xor(rm, 16));
    rm = fmaxf(rm, __shfl_xor(rm, 32));
    const float mn = fmaxf(m_i, rm);
    const float alpha = __expf(m_i - mn);
    m_i = mn;
    float ps = 0.f;
#pragma unroll
    for (int mi = 0; mi < 4; ++mi)
#pragma unroll
      for (int r = 0; r < 4; ++r) {
        const float p = __expf(s[mi][r] - mn);
        s[mi][r] = p;
        ps += p;
      }
    ps += __shfl_xor(ps, 16);
    ps += __shfl_xor(ps, 32);
    l_i = l_i * alpha + ps;
#pragma unroll
    for (int ni = 0; ni < 4; ++ni)
#pragma unroll
      for (int r = 0; r < 4; ++r) o[ni][r] *= alpha;

#pragma unroll
    for (int mi = 0; mi < 4; ++mi) {
      half4_t h;
      h[0] = (_Float16)s[mi][0]; h[1] = (_Float16)s[mi][1];
      h[2] = (_Float16)s[mi][2]; h[3] = (_Float16)s[mi][3];
      const int kloc = mi * 16 + quad * 4;
      const int chunk = kloc >> 3;
      *(half4_t*)(Pw + col * 64 + (((chunk ^ (col & 7)) << 3) | (kloc & 7))) = h;
    }
    const half8 p0 = frag_ld(Pw, col, quad);
    const half8 p1 = frag_ld(Pw, col, 4 + quad);

#pragma unroll
    for (int ni = 0; ni < 4; ++ni) {
      o[ni] = MFMA16(frag_ld(Vs, ni * 16 + col, quad), p0, o[ni]);
      o[ni] = MFMA16(frag_ld(Vs, ni * 16 + col, 4 + quad), p1, o[ni]);
    }
  }

  __syncthreads();
  f32x4* Ox = (f32x4*)&Pt[0][0];
  float* MlS = (float*)&KV[0][0];
  if (khalf == 1) {
#pragma unroll
    for (int ni = 0; ni < 4; ++ni) Ox[(qsub * 4 + ni) * 64 + ln] = o[ni];
    MlS[qsub * 64 + ln] = m_i;
    MlS[128 + qsub * 64 + ln] = l_i;
  }
  __syncthreads();
  if (khalf == 0) {
    const float m2 = MlS[qsub * 64 + ln];
    const float l2 = MlS[128 + qsub * 64 + ln];
    const float ms = fmaxf(m_i, m2);
    const float w1 = __expf(m_i - ms);
    const float w2 = __expf(m2 - ms);
    const float inv = 1.0f / (l_i * w1 + l2 * w2);
#pragma unroll
    for (int ni = 0; ni < 4; ++ni) {
      const f32x4 o2 = Ox[(qsub * 4 + ni) * 64 + ln];
      half4_t h;
#pragma unroll
      for (int r = 0; r < 4; ++r)
        h[r] = (_Float16)((o[ni][r] * w1 + o2[r] * w2) * inv);
      *(half4_t*)&AO[((size_t)(b * 1024 + qg)) * 1024 + hh * 64 + ni * 16 + quad * 4] = h;
    }
  }
}

extern "C" void kernel_launch(void* const* d_in, const int* in_sizes, int n_in,
                              void* d_out, int out_size, void* d_ws, size_t ws_size,
                              hipStream_t stream) {
  (void)in_sizes; (void)n_in; (void)out_size; (void)ws_size;
  const float* q = (const float*)d_in[0];
  const float* k = (const float*)d_in[1];
  const float* v = (const float*)d_in[2];
  const float* Wq = (const float*)d_in[3];
  const float* bq = (const float*)d_in[4];
  const float* Wk = (const float*)d_in[5];
  const float* bk = (const float*)d_in[6];
  const float* Wv = (const float*)d_in[7];
  const float* bv = (const float*)d_in[8];
  const float* Wo = (const float*)d_in[9];
  const float* bo = (const float*)d_in[10];
  const float* lb = (const float*)d_in[11];
  const int* kpm = (const int*)d_in[12];
  float* out = (float*)d_out;

  const size_t NT = (size_t)2 * 1024 * 1024;
  _Float16* q16 = (_Float16*)d_ws;
  _Float16* k16 = q16 + NT;
  _Float16* v16 = k16 + NT;
  _Float16* Qh = v16 + NT;
  _Float16* Kh = Qh + NT;
  _Float16* Vt = Kh + NT;
  _Float16* w16 = Vt + NT;  // 4 x 1M halves (Wq,Wk,Wv,Wo)
  _Float16* AO = q16;       // q16 dead after projections

  cvt_f32_f16<<<dim3(1024, 7), 256, 0, stream>>>(q, k, v, Wq, Wk, Wv, Wo,
                                                 q16, k16, v16, w16);
  mm8<<<dim3(8, 32, 3), 512, 0, stream>>>(q16, k16, v16, w16, bq, bk, bv,
                                          Qh, Kh, Vt, nullptr, 0);
  attn<<<dim3(32, 32), 256, 0, stream>>>(Qh, Kh, Vt, lb, kpm, AO);
  mm8<<<dim3(8, 32, 1), 512, 0, stream>>>(AO, nullptr, nullptr, w16 + 3 * NT / 2,
                                          bo, nullptr, nullptr, nullptr, nullptr,
                                          nullptr, out, 1);
}